// Round 2
// baseline (366.691 us; speedup 1.0000x reference)
//
#include <hip/hip_runtime.h>
#include <math.h>

// Problem constants (from reference)
#define NM       16     // total SH components l=0..3
#define NQ       32     // N_PSEUDO * N_MAX
#define CUT      5.0f
#define CAP      96     // per-node edge bucket capacity (max degree ~45 here)
#define TS       32     // edges per tile per wave
#define GPB      4      // nodes (waves) per block

typedef float v4f __attribute__((ext_vector_type(4)));

// ---------------------------------------------------------------------------
// Kernel 1: bin edges by destination node i, filtering r >= CUT (zero fcut).
// Stores {dx,dy,dz,species_j} per passing edge. One int atomic per edge.
// ---------------------------------------------------------------------------
__global__ __launch_bounds__(256) void edge_bin_kernel(
    const float* __restrict__ pos,      // [N][3]
    const float* __restrict__ cells,    // [1][3][3]
    const int*   __restrict__ species,  // [N]
    const int*   __restrict__ eidx,     // [2][E]
    const int*   __restrict__ eshift,   // [E][3]
    int*         __restrict__ counts,   // [N]
    float4*      __restrict__ buckets,  // [N][CAP]
    int E)
{
    const int e = blockIdx.x * blockDim.x + threadIdx.x;
    if (e >= E) return;

    const int i = eidx[e];
    const int j = eidx[E + e];

    float dx = pos[3 * j + 0] - pos[3 * i + 0];
    float dy = pos[3 * j + 1] - pos[3 * i + 1];
    float dz = pos[3 * j + 2] - pos[3 * i + 2];

    const int sx = eshift[3 * e + 0];
    const int sy = eshift[3 * e + 1];
    const int sz = eshift[3 * e + 2];
    dx += (float)sx * cells[0] + (float)sy * cells[3] + (float)sz * cells[6];
    dy += (float)sx * cells[1] + (float)sy * cells[4] + (float)sz * cells[7];
    dz += (float)sx * cells[2] + (float)sy * cells[5] + (float)sz * cells[8];

    const float r2 = dx * dx + dy * dy + dz * dz;
    if (r2 >= CUT * CUT) return;        // fcut == 0 -> exact zero contribution

    const int slot = atomicAdd(&counts[i], 1);
    if (slot < CAP)
        buckets[(size_t)i * CAP + slot] =
            make_float4(dx, dy, dz, __int_as_float(species[j]));
}

// ---------------------------------------------------------------------------
// Kernel 2: ONE WAVE PER NODE, 4 nodes per block, zero __syncthreads.
// Wave-synchronous LDS with explicit lgkmcnt fences.
//
// Per-wave data flow:
//   phase A: lanes 0..nb-1 each stage one edge into LDS as 12 ds_write_b128:
//            Y[16] (4 chunks, linear) + W[32] (8 chunks, XOR-swizzled by row)
//   phase B: all 64 lanes accumulate c: lane owns (m = lane>>2,
//            q = (lane&3)*8 .. +7)  ->  1 b32 + 2 b128 + 8 FMA per edge
//   phase C: c published to LDS (chunk-swizzled), then register 4x4 outer-
//            product tiles: per m-term 2 conflict-free b128 + 16 FMA; 16
//            nontemporal float4 stores per lane (full cachelines).
// ---------------------------------------------------------------------------
__global__ __launch_bounds__(256, 4) void node_fused_kernel(
    const float4* __restrict__ buckets, // [N][CAP]
    const int*    __restrict__ counts,  // [N]
    const float*  __restrict__ semb,    // [4][4]
    const float*  __restrict__ mu,      // [8]
    const float*  __restrict__ sigma,   // [1]
    float*        __restrict__ out,     // [N][4096]
    int N)
{
    const int tid  = threadIdx.x;
    const int lane = tid & 63;
    const int wv   = tid >> 6;
    const int node = blockIdx.x * GPB + wv;

    // per-wave tile: TS rows x 48 floats ([0..15] = Y, [16..47] = W chunks)
    __shared__ __align__(16) float sT[GPB][TS * 48];
    // per-wave c matrix [16][32], chunk-swizzled
    __shared__ __align__(16) float sC[GPB][NM * NQ];

    if (node >= N) return;              // no block-wide barriers anywhere -> safe

    const float sig    = sigma[0];
    const float inv2s2 = -1.0f / (2.0f * sig * sig);

    const int cnt = min(counts[node], CAP);

    const int m   = lane >> 2;          // owned c row (0..15)
    const int p4  = lane & 3;           // owned q block: q = p4*8 .. p4*8+7
    const int cw0 = p4 * 2;             // first owned W chunk

    v4f acc0 = {0.f, 0.f, 0.f, 0.f};    // c[m][p4*8 + 0..3]
    v4f acc1 = {0.f, 0.f, 0.f, 0.f};    // c[m][p4*8 + 4..7]

    float* const tile = &sT[wv][0];

    for (int base = 0; base < cnt; base += TS) {
        const int nb = min(cnt - base, TS);

        // WAR: previous tile's LDS reads retire before overwriting
        asm volatile("s_waitcnt lgkmcnt(0)" ::: "memory");
        __builtin_amdgcn_sched_barrier(0);

        if (lane < nb) {
            const float4 b = buckets[(size_t)node * CAP + base + lane];
            const float dx = b.x, dy = b.y, dz = b.z;
            const float r2 = dx * dx + dy * dy + dz * dz + 1e-12f;
            const float r  = sqrtf(r2);
            const float invr = 1.0f / r;
            const float x = dx * invr, y = dy * invr, z = dz * invr;
            const float x2 = x * x, y2 = y * y, z2 = z * z;

            v4f* rowY = (v4f*)&tile[lane * 48];
            v4f y0 = {0.28209479177387814f,
                      0.4886025119029199f * y,
                      0.4886025119029199f * z,
                      0.4886025119029199f * x};
            v4f y1 = {1.0925484305920792f * x * y,
                      1.0925484305920792f * y * z,
                      0.31539156525252005f * (3.0f * z2 - 1.0f),
                      1.0925484305920792f * x * z};
            v4f y2v = {0.5462742152960396f * (x2 - y2),
                       0.5900435899266435f * y * (3.0f * x2 - y2),
                       2.890611442640554f  * x * y * z,
                       0.4570457994644658f * y * (5.0f * z2 - 1.0f)};
            v4f y3 = {0.3731763325901154f * z * (5.0f * z2 - 3.0f),
                      0.4570457994644658f * x * (5.0f * z2 - 1.0f),
                      1.445305721320277f  * z * (x2 - y2),
                      0.5900435899266435f * x * (x2 - 3.0f * y2)};
            rowY[0] = y0; rowY[1] = y1; rowY[2] = y2v; rowY[3] = y3;

            const float fcut = 0.5f * (__cosf(0.62831853071795864f * r) + 1.0f);
            const int sj = __float_as_int(b.w);
            const v4f ej = ((const v4f*)semb)[sj];   // 64B table, L1-resident

            float R[8];
#pragma unroll
            for (int n = 0; n < 8; ++n) {
                const float dr = r - mu[n];
                R[n] = __expf(dr * dr * inv2s2) * fcut;
            }
            const v4f rlo = {R[0], R[1], R[2], R[3]};
            const v4f rhi = {R[4], R[5], R[6], R[7]};

            // W chunks XOR-swizzled by row -> 2-way max on writes (free),
            // broadcast on reads (row uniform in phase B)
            v4f* rowW = (v4f*)&tile[lane * 48 + 16];
            const int sw = lane & 7;
            rowW[(0) ^ sw] = ej[0] * rlo; rowW[(1) ^ sw] = ej[0] * rhi;
            rowW[(2) ^ sw] = ej[1] * rlo; rowW[(3) ^ sw] = ej[1] * rhi;
            rowW[(4) ^ sw] = ej[2] * rlo; rowW[(5) ^ sw] = ej[2] * rhi;
            rowW[(6) ^ sw] = ej[3] * rlo; rowW[(7) ^ sw] = ej[3] * rhi;
        }

        // RAW: staging visible to all lanes of this wave
        asm volatile("s_waitcnt lgkmcnt(0)" ::: "memory");
        __builtin_amdgcn_sched_barrier(0);

        for (int e = 0; e < nb; ++e) {
            const float* rowp = &tile[e * 48];
            const float ym = rowp[m];                       // 16 addrs, no conflict
            const int es = e & 7;
            const v4f wlo = ((const v4f*)(rowp + 16))[(cw0)     ^ es];
            const v4f whi = ((const v4f*)(rowp + 16))[(cw0 + 1) ^ es];
            acc0 += ym * wlo;
            acc1 += ym * whi;
        }
    }

    // phase C: publish c (chunk-swizzled: phys chunk = c ^ (row&7))
    float* const cw_ = &sC[wv][0];
    ((v4f*)cw_)[m * 8 + ((cw0)     ^ (m & 7))] = acc0;
    ((v4f*)cw_)[m * 8 + ((cw0 + 1) ^ (m & 7))] = acc1;
    asm volatile("s_waitcnt lgkmcnt(0)" ::: "memory");
    __builtin_amdgcn_sched_barrier(0);

    // Power spectrum: lane owns a 4x4 output tile per l:
    //   rows q = qt*4+j (j=0..3), cols r = rt*4..rt*4+3
    const float cg[4] = {1.0f, 0.57735026918962576f,
                         0.44721359549995794f, 0.37796447300922723f};
    const int qt = lane >> 3;           // 0..7
    const int rt = lane & 7;            // 0..7

    v4f* op = (v4f*)out + (size_t)node * 1024;

#pragma unroll
    for (int l = 0; l < 4; ++l) {
        const int mb = l * l;
        const int mc = 2 * l + 1;
        v4f s0 = {0.f,0.f,0.f,0.f}, s1 = {0.f,0.f,0.f,0.f};
        v4f s2 = {0.f,0.f,0.f,0.f}, s3 = {0.f,0.f,0.f,0.f};
        for (int mm = 0; mm < mc; ++mm) {
            const int row = mb + mm;
            const v4f* crow4 = (const v4f*)cw_ + row * 8;
            const int rs = row & 7;
            const v4f qv = crow4[qt ^ rs];              // 8 addrs, no conflict
            const v4f rv = crow4[rt ^ rs];              // 8 addrs, no conflict
            s0 += qv[0] * rv;
            s1 += qv[1] * rv;
            s2 += qv[2] * rv;
            s3 += qv[3] * rv;
        }
        const float g = cg[l];
        __builtin_nontemporal_store(s0 * g, &op[l * 256 + (qt * 4 + 0) * 8 + rt]);
        __builtin_nontemporal_store(s1 * g, &op[l * 256 + (qt * 4 + 1) * 8 + rt]);
        __builtin_nontemporal_store(s2 * g, &op[l * 256 + (qt * 4 + 2) * 8 + rt]);
        __builtin_nontemporal_store(s3 * g, &op[l * 256 + (qt * 4 + 3) * 8 + rt]);
    }
}

// ---------------------------------------------------------------------------
extern "C" void kernel_launch(void* const* d_in, const int* in_sizes, int n_in,
                              void* d_out, int out_size, void* d_ws, size_t ws_size,
                              hipStream_t stream) {
    const float* pos     = (const float*)d_in[0];
    const float* cells   = (const float*)d_in[1];
    const int*   species = (const int*)  d_in[2];
    const int*   eidx    = (const int*)  d_in[3];
    const int*   eshift  = (const int*)  d_in[4];
    const float* semb    = (const float*)d_in[5];
    const float* mu      = (const float*)d_in[6];
    const float* sigma   = (const float*)d_in[7];
    float*       out     = (float*)d_out;

    const int N = in_sizes[0] / 3;
    const int E = in_sizes[3] / 2;

    float4* buckets = (float4*)d_ws;                         // [N][CAP] x 16B
    const size_t bucket_bytes = (size_t)N * CAP * sizeof(float4);
    int* counts = (int*)((char*)d_ws + bucket_bytes);        // [N]

    hipMemsetAsync(counts, 0, (size_t)N * sizeof(int), stream);

    edge_bin_kernel<<<(E + 255) / 256, 256, 0, stream>>>(
        pos, cells, species, eidx, eshift, counts, buckets, E);

    node_fused_kernel<<<(N + GPB - 1) / GPB, 256, 0, stream>>>(
        buckets, counts, semb, mu, sigma, out, N);
}